// Round 5
// baseline (7984.090 us; speedup 1.0000x reference)
//
#include <hip/hip_runtime.h>
#include <math.h>

typedef unsigned short ushort_t;
typedef __attribute__((ext_vector_type(8))) short bf16x8;   // 8 bf16 bit-patterns (4 VGPRs)
typedef __attribute__((ext_vector_type(4))) float f32x4;

#define SCALE 0.03608439182435161f  // 1/sqrt(768)

__device__ __forceinline__ ushort_t f2bf(float f) {
  unsigned u = __float_as_uint(f);
  return (ushort_t)((u + 0x7FFFu + ((u >> 16) & 1u)) >> 16);  // RNE
}
__device__ __forceinline__ float bf2f(ushort_t h) {
  return __uint_as_float(((unsigned)h) << 16);
}

// ---------------------------------------------------------------------------
// 128x128xK MFMA GEMM, NT form (both operands rows[idx][k], k-contiguous).
// BK=32, 4 waves (2x2), wave = 64x64 = 4x4 frags of 16x16x32 bf16 MFMA.
// LDS XOR-swizzle on 16B granules: granule' = granule ^ ((row>>1)&3).
// AM/BM: 0 = fp32 source split to hi/lo during staging
//        1 = pre-split hi/lo planes (copy); aSplitS: per-s pair-plane layout
//        2 = single bf16 plane (copy)
// EPI:   0 = fp32 store (scaled); 1 = hi/lo bf16 store (zMode = per-s pairs;
//            caller MUST set Clo — for zMode pair-planes Clo = Chi + 393216)
// TRIPLE: hi*hi + hi*lo + lo*hi
// ---------------------------------------------------------------------------
struct MMP {
  const float* Af;
  const ushort_t* Ahi; const ushort_t* Alo;
  long aLd, aZ; int aSplitS;
  const float* Bf;
  const ushort_t* Bhi; const ushort_t* Blo;
  long bLd, bZ;
  float* Cf; float cScale;
  ushort_t* Chi; ushort_t* Clo;
  long cLd, cZ;
  int zMode;
  int K;
};

template <int AM, int BM, int EPI, bool TRIPLE>
__global__ __launch_bounds__(256) void mm(MMP P)
{
  __shared__ ushort_t lds[16384];   // Ah|Al|Bh|Bl, 4096 each (32 KB)
  ushort_t* Ah = lds;
  ushort_t* Al = lds + 4096;
  ushort_t* Bh = lds + 8192;
  ushort_t* Bl = lds + 12288;

  const int tid = threadIdx.x;
  const int z = blockIdx.z;
  int bx = blockIdx.x, by = blockIdx.y;
  if (gridDim.z == 1) {                       // XCD-aware swizzle (bijective)
    int nwg = gridDim.x * gridDim.y;
    if ((nwg & 7) == 0) {
      int id = by * gridDim.x + bx;
      int q = nwg >> 3;
      int wid = (id & 7) * q + (id >> 3);
      bx = wid % gridDim.x;
      by = wid / gridDim.x;
    }
  }
  const int m0 = by * 128, n0 = bx * 128;

  const int lane = tid & 63;
  const int wave = tid >> 6;
  const int wm = (wave >> 1) * 64, wn = (wave & 1) * 64;
  const int lr = lane & 15, g = lane >> 4;

  f32x4 acc[4][4];
  #pragma unroll
  for (int i = 0; i < 4; ++i)
    #pragma unroll
    for (int j = 0; j < 4; ++j) {
      f32x4 zv = {0.f, 0.f, 0.f, 0.f};
      acc[i][j] = zv;
    }

  for (int k0 = 0; k0 < P.K; k0 += 32) {
    // ---------------- stage A ----------------
    if constexpr (AM == 0) {
      const float* A = P.Af + (long)z * P.aZ;
      #pragma unroll
      for (int rep = 0; rep < 4; ++rep) {
        int idx = tid + rep * 256;
        int row = idx >> 3, q = idx & 7;
        float4 v = *(const float4*)(A + (long)(m0 + row) * P.aLd + k0 + q * 4);
        int off = row * 32 + (((q >> 1) ^ ((row >> 1) & 3)) << 3) + ((q & 1) << 2);
        ushort_t hh[4], ll[4];
        hh[0] = f2bf(v.x); ll[0] = f2bf(v.x - bf2f(hh[0]));
        hh[1] = f2bf(v.y); ll[1] = f2bf(v.y - bf2f(hh[1]));
        hh[2] = f2bf(v.z); ll[2] = f2bf(v.z - bf2f(hh[2]));
        hh[3] = f2bf(v.w); ll[3] = f2bf(v.w - bf2f(hh[3]));
        *(uint2*)(Ah + off) = *(uint2*)hh;
        *(uint2*)(Al + off) = *(uint2*)ll;
      }
    } else if constexpr (AM == 1) {
      #pragma unroll
      for (int rep = 0; rep < 2; ++rep) {
        int idx = tid + rep * 256;
        int row = idx >> 2, h8 = idx & 3;
        int off = row * 32 + ((h8 ^ ((row >> 1) & 3)) << 3);
        int rg = m0 + row;
        const ushort_t *As, *Als;
        if (P.aSplitS) {
          long base = (long)(rg >> 9) * 786432 + (long)(rg & 511) * 768 + k0 + h8 * 8;
          As = P.Ahi + base; Als = P.Ahi + base + 393216;
        } else {
          long base = (long)rg * P.aLd + k0 + h8 * 8;
          As = P.Ahi + (long)z * P.aZ + base;
          Als = P.Alo + (long)z * P.aZ + base;
        }
        *(uint4*)(Ah + off) = *(const uint4*)As;
        *(uint4*)(Al + off) = *(const uint4*)Als;
      }
    } else {
      const ushort_t* As = P.Ahi + (long)z * P.aZ;
      #pragma unroll
      for (int rep = 0; rep < 2; ++rep) {
        int idx = tid + rep * 256;
        int row = idx >> 2, h8 = idx & 3;
        int off = row * 32 + ((h8 ^ ((row >> 1) & 3)) << 3);
        *(uint4*)(Ah + off) = *(const uint4*)(As + (long)(m0 + row) * P.aLd + k0 + h8 * 8);
      }
    }
    // ---------------- stage B ----------------
    if constexpr (BM == 0) {
      const float* B = P.Bf + (long)z * P.bZ;
      #pragma unroll
      for (int rep = 0; rep < 4; ++rep) {
        int idx = tid + rep * 256;
        int row = idx >> 3, q = idx & 7;
        float4 v = *(const float4*)(B + (long)(n0 + row) * P.bLd + k0 + q * 4);
        int off = row * 32 + (((q >> 1) ^ ((row >> 1) & 3)) << 3) + ((q & 1) << 2);
        ushort_t hh[4], ll[4];
        hh[0] = f2bf(v.x); ll[0] = f2bf(v.x - bf2f(hh[0]));
        hh[1] = f2bf(v.y); ll[1] = f2bf(v.y - bf2f(hh[1]));
        hh[2] = f2bf(v.z); ll[2] = f2bf(v.z - bf2f(hh[2]));
        hh[3] = f2bf(v.w); ll[3] = f2bf(v.w - bf2f(hh[3]));
        *(uint2*)(Bh + off) = *(uint2*)hh;
        *(uint2*)(Bl + off) = *(uint2*)ll;
      }
    } else {
      const ushort_t* Bs = P.Bhi + (long)z * P.bZ;
      #pragma unroll
      for (int rep = 0; rep < 2; ++rep) {
        int idx = tid + rep * 256;
        int row = idx >> 2, h8 = idx & 3;
        int off = row * 32 + ((h8 ^ ((row >> 1) & 3)) << 3);
        long gsrc = (long)(n0 + row) * P.bLd + k0 + h8 * 8;
        *(uint4*)(Bh + off) = *(const uint4*)(Bs + gsrc);
        if constexpr (BM == 1) {
          const ushort_t* Bls = P.Blo + (long)z * P.bZ;
          *(uint4*)(Bl + off) = *(const uint4*)(Bls + gsrc);
        }
      }
    }
    __syncthreads();

    // ---------------- compute ----------------
    bf16x8 ar[4], br[4];
    #pragma unroll
    for (int i = 0; i < 4; ++i) {
      int row = wm + i * 16 + lr;
      ar[i] = *(const bf16x8*)(Ah + row * 32 + ((g ^ ((row >> 1) & 3)) << 3));
    }
    #pragma unroll
    for (int j = 0; j < 4; ++j) {
      int row = wn + j * 16 + lr;
      br[j] = *(const bf16x8*)(Bh + row * 32 + ((g ^ ((row >> 1) & 3)) << 3));
    }
    #pragma unroll
    for (int i = 0; i < 4; ++i)
      #pragma unroll
      for (int j = 0; j < 4; ++j)
        acc[i][j] = __builtin_amdgcn_mfma_f32_16x16x32_bf16(ar[i], br[j], acc[i][j], 0, 0, 0);

    if constexpr (TRIPLE) {
      #pragma unroll
      for (int j = 0; j < 4; ++j) {
        int row = wn + j * 16 + lr;
        bf16x8 blv = *(const bf16x8*)(Bl + row * 32 + ((g ^ ((row >> 1) & 3)) << 3));
        #pragma unroll
        for (int i = 0; i < 4; ++i)
          acc[i][j] = __builtin_amdgcn_mfma_f32_16x16x32_bf16(ar[i], blv, acc[i][j], 0, 0, 0);
      }
      #pragma unroll
      for (int i = 0; i < 4; ++i) {
        int row = wm + i * 16 + lr;
        bf16x8 alv = *(const bf16x8*)(Al + row * 32 + ((g ^ ((row >> 1) & 3)) << 3));
        #pragma unroll
        for (int j = 0; j < 4; ++j)
          acc[i][j] = __builtin_amdgcn_mfma_f32_16x16x32_bf16(alv, br[j], acc[i][j], 0, 0, 0);
      }
    }
    __syncthreads();
  }

  // ---------------- epilogue (C/D: col = lane&15, row = (lane>>4)*4 + reg) ---
  #pragma unroll
  for (int i = 0; i < 4; ++i) {
    #pragma unroll
    for (int j = 0; j < 4; ++j) {
      int colG = n0 + wn + j * 16 + lr;
      #pragma unroll
      for (int r = 0; r < 4; ++r) {
        int rowG = m0 + wm + i * 16 + g * 4 + r;
        float v = acc[i][j][r];
        if constexpr (EPI == 0) {
          P.Cf[(long)z * P.cZ + (long)rowG * P.cLd + colG] = v * P.cScale;
        } else {
          ushort_t hi = f2bf(v);
          ushort_t lo = f2bf(v - bf2f(hi));
          long off;
          if (P.zMode) off = (long)(rowG >> 9) * 786432 + (long)(rowG & 511) * 768 + colG;
          else         off = (long)rowG * P.cLd + colG;
          P.Chi[off] = hi;
          P.Clo[off] = lo;
        }
      }
    }
  }
}

// ---------------------------------------------------------------------------
// fsc2: fused scores+softmax, SINGLE hi*hi MFMA pass + exact correction of
// near-max candidates. Per s: 8 blocks of 64 rows x 512 cols. 512 thr = 8
// waves; wave w owns cols [w*64, w*64+64).
// Logits (unscaled) std ~ 21000; approx error (missing hi*lo terms) std ~ 33.
// Candidates: approx > rowmax - 390 (~14 scaled, ~11 sigma) -> recompute
// exact fp32 dot of (Zhi+Zlo) row vs fp32 X column. Tail entries keep approx
// (true weights < e^-8 -> negligible).
// Block->XCD affinity: id = (group*8 + tile)*8 + (z&7), so all 8 tiles of one
// s share id%8 (same XCD) and are adjacent in dispatch order -> B panel is
// fetched once per s and shared via L2.
// ---------------------------------------------------------------------------
__global__ __launch_bounds__(512) void fsc2(const ushort_t* __restrict__ Zb,
                                            const ushort_t* __restrict__ Xsp,
                                            const float* __restrict__ X,
                                            ushort_t* __restrict__ Pm, int s0)
{
  __shared__ ushort_t lds[18432];  // Ah(2048) | Bh(16384) = 36 KB
  ushort_t* Ah = lds;
  ushort_t* Bh = lds + 2048;

  int id = blockIdx.x;
  int nS = gridDim.x >> 3;
  int z, tile;
  if ((nS & 7) == 0) {
    int c = id & 7, t = id >> 3;
    tile = t & 7;
    z = c + ((t >> 3) << 3);
  } else {
    tile = id & 7;
    z = id >> 3;
  }
  const int m0 = tile * 64;

  const ushort_t* Az = Zb + (long)z * 786432;   // Z_s hi; lo at +393216
  const ushort_t* Bz = Xsp + (long)z * 786432;  // X_s hi plane
  const float*    Xf = X + (long)(s0 + z) * 393216;

  const int tid = threadIdx.x;
  const int lane = tid & 63;
  const int wave = tid >> 6;
  const int wn = wave * 64;
  const int lr = lane & 15, g = lane >> 4;

  f32x4 acc[4][4];
  #pragma unroll
  for (int i = 0; i < 4; ++i)
    #pragma unroll
    for (int j = 0; j < 4; ++j) {
      f32x4 zv = {0.f, 0.f, 0.f, 0.f};
      acc[i][j] = zv;
    }

  for (int k0 = 0; k0 < 768; k0 += 32) {
    if (tid < 256) {
      int row = tid >> 2, h8 = tid & 3;
      int off = row * 32 + ((h8 ^ ((row >> 1) & 3)) << 3);
      *(uint4*)(Ah + off) = *(const uint4*)(Az + (long)(m0 + row) * 768 + k0 + h8 * 8);
    }
    #pragma unroll
    for (int rep = 0; rep < 4; ++rep) {
      int e = tid + rep * 512;
      int row = e >> 2, h8 = e & 3;
      int off = row * 32 + ((h8 ^ ((row >> 1) & 3)) << 3);
      *(uint4*)(Bh + off) = *(const uint4*)(Bz + (long)row * 768 + k0 + h8 * 8);
    }
    __syncthreads();

    bf16x8 ar[4];
    #pragma unroll
    for (int i = 0; i < 4; ++i) {
      int row = i * 16 + lr;
      ar[i] = *(const bf16x8*)(Ah + row * 32 + ((g ^ ((row >> 1) & 3)) << 3));
    }
    #pragma unroll
    for (int j = 0; j < 4; ++j) {
      int row = wn + j * 16 + lr;
      bf16x8 bv = *(const bf16x8*)(Bh + row * 32 + ((g ^ ((row >> 1) & 3)) << 3));
      #pragma unroll
      for (int i = 0; i < 4; ++i)
        acc[i][j] = __builtin_amdgcn_mfma_f32_16x16x32_bf16(ar[i], bv, acc[i][j], 0, 0, 0);
    }
    __syncthreads();
  }

  // ---- reductions overlay on LDS (all staged reads are done) ----
  float* redf = (float*)lds;        // [64][12] padded rows
  float* reds = redf + 768;

  // row max of APPROX (unscaled)
  float mrU[4][4];
  #pragma unroll
  for (int i = 0; i < 4; ++i)
    #pragma unroll
    for (int r = 0; r < 4; ++r) {
      float mx = acc[i][0][r];
      #pragma unroll
      for (int j = 1; j < 4; ++j) mx = fmaxf(mx, acc[i][j][r]);
      #pragma unroll
      for (int off = 8; off >= 1; off >>= 1) mx = fmaxf(mx, __shfl_xor(mx, off, 64));
      if (lr == 0) redf[(i * 16 + g * 4 + r) * 12 + wave] = mx;
    }
  __syncthreads();
  #pragma unroll
  for (int i = 0; i < 4; ++i)
    #pragma unroll
    for (int r = 0; r < 4; ++r) {
      int row = i * 16 + g * 4 + r;
      float4 a = *(const float4*)&redf[row * 12];
      float4 b = *(const float4*)&redf[row * 12 + 4];
      mrU[i][r] = fmaxf(fmaxf(fmaxf(a.x, a.y), fmaxf(a.z, a.w)),
                        fmaxf(fmaxf(b.x, b.y), fmaxf(b.z, b.w)));
    }

  // ---- exact recompute of near-max candidates (rare; divergent ok) ----
  #pragma unroll
  for (int i = 0; i < 4; ++i)
    #pragma unroll
    for (int j = 0; j < 4; ++j)
      #pragma unroll
      for (int r = 0; r < 4; ++r) {
        if (acc[i][j][r] > mrU[i][r] - 390.0f) {
          int rowS = m0 + i * 16 + g * 4 + r;
          int colS = wn + j * 16 + lr;
          const ushort_t* zr = Az + (long)rowS * 768;
          const ushort_t* zl = zr + 393216;
          const float* xr = Xf + (long)colS * 768;
          float ex = 0.f;
          for (int k = 0; k < 768; k += 8) {
            ushort_t zh8[8], zl8[8];
            *(uint4*)zh8 = *(const uint4*)(zr + k);
            *(uint4*)zl8 = *(const uint4*)(zl + k);
            float4 xa = *(const float4*)(xr + k);
            float4 xb = *(const float4*)(xr + k + 4);
            ex += (bf2f(zh8[0]) + bf2f(zl8[0])) * xa.x;
            ex += (bf2f(zh8[1]) + bf2f(zl8[1])) * xa.y;
            ex += (bf2f(zh8[2]) + bf2f(zl8[2])) * xa.z;
            ex += (bf2f(zh8[3]) + bf2f(zl8[3])) * xa.w;
            ex += (bf2f(zh8[4]) + bf2f(zl8[4])) * xb.x;
            ex += (bf2f(zh8[5]) + bf2f(zl8[5])) * xb.y;
            ex += (bf2f(zh8[6]) + bf2f(zl8[6])) * xb.z;
            ex += (bf2f(zh8[7]) + bf2f(zl8[7])) * xb.w;
          }
          acc[i][j][r] = ex;
        }
      }

  // ---- exp/sum (softmax invariant to the max shift; arg <= ~+15 scaled) ----
  #pragma unroll
  for (int i = 0; i < 4; ++i)
    #pragma unroll
    for (int r = 0; r < 4; ++r) {
      float s = 0.f;
      #pragma unroll
      for (int j = 0; j < 4; ++j) {
        float e = __expf((acc[i][j][r] - mrU[i][r]) * SCALE);
        acc[i][j][r] = e;
        s += e;
      }
      #pragma unroll
      for (int off = 8; off >= 1; off >>= 1) s += __shfl_xor(s, off, 64);
      if (lr == 0) reds[(i * 16 + g * 4 + r) * 12 + wave] = s;
    }
  __syncthreads();
  ushort_t* Pz = Pm + (long)z * 262144 + (long)m0 * 512;
  #pragma unroll
  for (int i = 0; i < 4; ++i)
    #pragma unroll
    for (int r = 0; r < 4; ++r) {
      int row = i * 16 + g * 4 + r;
      float4 a = *(const float4*)&reds[row * 12];
      float4 b = *(const float4*)&reds[row * 12 + 4];
      float inv = 1.0f / (a.x + a.y + a.z + a.w + b.x + b.y + b.z + b.w);
      #pragma unroll
      for (int j = 0; j < 4; ++j)
        Pz[(long)row * 512 + wn + j * 16 + lr] = f2bf(acc[i][j][r] * inv);
    }
}

// ---------------------------------------------------------------------------
// prep: per s, split X -> (hi,lo) bf16 pair-planes AND write V^T hi-plane.
// One read of X serves both. 64x64 tiles.
// ---------------------------------------------------------------------------
__global__ __launch_bounds__(256) void prep(const float* __restrict__ X,
                                            ushort_t* __restrict__ Xsp,
                                            ushort_t* __restrict__ Xt, int s0)
{
  const int si = blockIdx.z;
  const long s = s0 + si;
  const int b0 = blockIdx.x * 64, e0 = blockIdx.y * 64;
  __shared__ float tile[64][65];
  const int t = threadIdx.x;
  const int bloc = t >> 4, eq = t & 15;
  ushort_t* Xh = Xsp + (long)si * 786432;
  #pragma unroll
  for (int r = 0; r < 4; ++r) {
    int b = bloc + r * 16;
    float4 v = *(const float4*)(X + (s * 512 + b0 + b) * 768 + e0 + eq * 4);
    tile[b][eq * 4 + 0] = v.x; tile[b][eq * 4 + 1] = v.y;
    tile[b][eq * 4 + 2] = v.z; tile[b][eq * 4 + 3] = v.w;
    ushort_t hh[4], ll[4];
    hh[0] = f2bf(v.x); ll[0] = f2bf(v.x - bf2f(hh[0]));
    hh[1] = f2bf(v.y); ll[1] = f2bf(v.y - bf2f(hh[1]));
    hh[2] = f2bf(v.z); ll[2] = f2bf(v.z - bf2f(hh[2]));
    hh[3] = f2bf(v.w); ll[3] = f2bf(v.w - bf2f(hh[3]));
    long dst = (long)(b0 + b) * 768 + e0 + eq * 4;
    *(uint2*)(Xh + dst)          = *(uint2*)hh;
    *(uint2*)(Xh + 393216 + dst) = *(uint2*)ll;
  }
  __syncthreads();
  const int e = t & 63, bq = t >> 6;
  ushort_t tmp[16];
  #pragma unroll
  for (int i = 0; i < 16; ++i) tmp[i] = f2bf(tile[bq * 16 + i][e]);
  ushort_t* dst = Xt + (long)si * 393216 + (long)(e0 + e) * 512 + b0 + bq * 16;
  *(uint4*)(dst)     = *(uint4*)&tmp[0];
  *(uint4*)(dst + 8) = *(uint4*)&tmp[8];
}

// ---------------------------------------------------------------------------
extern "C" void kernel_launch(void* const* d_in, const int* in_sizes, int n_in,
                              void* d_out, int out_size, void* d_ws, size_t ws_size,
                              hipStream_t stream) {
  const float* X = (const float*)d_in[0];
  const float* R = (const float*)d_in[1];  // rotation_params
  const float* W = (const float*)d_in[2];  // entangle_params
  float* out = (float*)d_out;
  char* ws = (char*)d_ws;

  // ws: H hi/lo (768x768 each) | Xsplit[SCI] pair-planes | Xt[SCI] | Pm[SCI]
  ushort_t* Hhi = (ushort_t*)ws;
  ushort_t* Hlo = Hhi + 768 * 768;
  const size_t hB   = 2ull * 768 * 768 * 2;                      // 2,359,296
  const size_t perS = 786432ull * 2 + 393216ull * 2 + 262144ull * 2;  // 2,883,584
  long SCI = 1;
  if (ws_size > hB + perS) SCI = (long)((ws_size - hB) / perS);
  if (SCI > 512) SCI = 512;
  if (SCI >= 8) SCI &= ~7L;     // keep chunks multiples of 8 for XCD affinity
  if (SCI < 1) SCI = 1;
  ushort_t* Xsp = (ushort_t*)(ws + hB);
  ushort_t* Xt  = Xsp + (long)SCI * 786432;
  ushort_t* Pm  = Xt + (long)SCI * 393216;

  // ---- K0: H = W * R^T  (768x768, triple), split-stored hi/lo ----
  {
    MMP p{};
    p.Af = W;  p.aLd = 768; p.aZ = 0;
    p.Bf = R;  p.bLd = 768; p.bZ = 0;
    p.Chi = Hhi; p.Clo = Hlo; p.cLd = 768; p.zMode = 0;
    p.K = 768;
    mm<0, 0, 1, true><<<dim3(6, 6, 1), 256, 0, stream>>>(p);
  }

  for (long s0 = 0; s0 < 512; s0 += SCI) {
    int cur = (int)((512 - s0 < SCI) ? (512 - s0) : SCI);

    // ---- prep: X_s -> split pair-planes + V^T hi-plane ----
    prep<<<dim3(8, 12, cur), 256, 0, stream>>>(X, Xsp, Xt, (int)s0);

    // ---- K1: Z_chunk = X_chunk * H^T (triple) -> d_out pair-planes ----
    {
      MMP p{};
      p.Ahi = Xsp; p.aSplitS = 1; p.aLd = 768; p.aZ = 0;
      p.Bhi = Hhi; p.Blo = Hlo; p.bLd = 768; p.bZ = 0;
      p.Chi = (ushort_t*)d_out + s0 * 786432;
      p.Clo = p.Chi + 393216;   // zMode epilogue writes Clo[off] too
      p.zMode = 1;
      p.K = 768;
      mm<1, 1, 1, true><<<dim3(6, 4 * cur, 1), 256, 0, stream>>>(p);
    }

    // ---- fsc2: P = softmax(SCALE * Z X^T), single-pass + exact correction ----
    fsc2<<<dim3(8 * cur), 512, 0, stream>>>((const ushort_t*)d_out + s0 * 786432,
                                            Xsp, X, Pm, (int)s0);

    // ---- K4: out_s = P * V (single bf16), overwrites Z_s in d_out ----
    {
      MMP q{};
      q.Ahi = Pm; q.aLd = 512; q.aZ = 262144; q.aSplitS = 0;
      q.Bhi = Xt; q.bLd = 512; q.bZ = 393216;
      q.Cf = out + s0 * 393216; q.cLd = 768; q.cZ = 393216; q.cScale = 1.0f;
      q.K = 512;
      mm<2, 2, 0, false><<<dim3(6, 4, cur), 256, 0, stream>>>(q);
    }
  }
}

// Round 6
// 3059.098 us; speedup vs baseline: 2.6099x; 2.6099x over previous
//
#include <hip/hip_runtime.h>
#include <hip/hip_bf16.h>
#include <math.h>

typedef unsigned short ushort_t;
typedef __attribute__((ext_vector_type(8))) short bf16x8;   // 8 bf16 (4 VGPRs)
typedef __attribute__((ext_vector_type(4))) float f32x4;

#define SCALE 0.03608439182435161f  // 1/sqrt(768)

__device__ __forceinline__ ushort_t f2bf(float f) {
  unsigned u = __float_as_uint(f);
  return (ushort_t)((u + 0x7FFFu + ((u >> 16) & 1u)) >> 16);  // RNE
}
__device__ __forceinline__ float bf2f(ushort_t h) {
  return __uint_as_float(((unsigned)h) << 16);
}

// split float4 -> hi/lo bf16 planes via v_cvt_pk. lo = exact fp32 residual of
// hi, so hi+lo precision (~2^-17 rel) holds regardless of hi rounding detail.
__device__ __forceinline__ void split4(float4 v, ushort_t* hh, ushort_t* ll) {
  __hip_bfloat162 h01 = __float22bfloat162_rn(make_float2(v.x, v.y));
  __hip_bfloat162 h23 = __float22bfloat162_rn(make_float2(v.z, v.w));
  unsigned u01 = *(unsigned*)&h01, u23 = *(unsigned*)&h23;
  float l0 = v.x - __uint_as_float((u01 & 0xFFFFu) << 16);
  float l1 = v.y - __uint_as_float(u01 & 0xFFFF0000u);
  float l2 = v.z - __uint_as_float((u23 & 0xFFFFu) << 16);
  float l3 = v.w - __uint_as_float(u23 & 0xFFFF0000u);
  __hip_bfloat162 g01 = __float22bfloat162_rn(make_float2(l0, l1));
  __hip_bfloat162 g23 = __float22bfloat162_rn(make_float2(l2, l3));
  *(unsigned*)&hh[0] = u01; *(unsigned*)&hh[2] = u23;
  *(unsigned*)&ll[0] = *(unsigned*)&g01; *(unsigned*)&ll[2] = *(unsigned*)&g23;
}

// ---------------------------------------------------------------------------
// mm: 128x128xK MFMA GEMM, NT form, bf16x3 triple product. Used for:
//   K0: H = W * R^T -> planar hi/lo planes in ws      (zMode=0)
//   K1: Z = X * H^T -> row-interleaved slots in d_out (zMode=1:
//       slot row r of s: ushort off = s*786432 + r*1536; hi [0,768), lo [768,1536))
// AM=0: fp32 A split in staging. BM: 0 = fp32 split, 1 = pre-split planes.
// ---------------------------------------------------------------------------
struct MMP {
  const float* Af;  long aLd;
  const float* Bf;
  const ushort_t* Bhi; const ushort_t* Blo; long bLd;
  ushort_t* Chi; ushort_t* Clo; long cLd;
  int zMode;
  int K;
};

template <int BM>
__global__ __launch_bounds__(256) void mm(MMP P)
{
  __shared__ ushort_t lds[16384];   // Ah|Al|Bh|Bl, 4096 each (32 KB)
  ushort_t* Ah = lds;
  ushort_t* Al = lds + 4096;
  ushort_t* Bh = lds + 8192;
  ushort_t* Bl = lds + 12288;

  const int tid = threadIdx.x;
  int bx = blockIdx.x, by = blockIdx.y;
  {                                           // XCD-aware bijective swizzle
    int nwg = gridDim.x * gridDim.y;
    if ((nwg & 7) == 0) {
      int id = by * gridDim.x + bx;
      int q = nwg >> 3;
      int wid = (id & 7) * q + (id >> 3);
      bx = wid % gridDim.x;
      by = wid / gridDim.x;
    }
  }
  const int m0 = by * 128, n0 = bx * 128;

  const int lane = tid & 63;
  const int wave = tid >> 6;
  const int wm = (wave >> 1) * 64, wn = (wave & 1) * 64;
  const int lr = lane & 15, g = lane >> 4;

  f32x4 acc[4][4];
  #pragma unroll
  for (int i = 0; i < 4; ++i)
    #pragma unroll
    for (int j = 0; j < 4; ++j) {
      f32x4 zv = {0.f, 0.f, 0.f, 0.f};
      acc[i][j] = zv;
    }

  for (int k0 = 0; k0 < P.K; k0 += 32) {
    // stage A (fp32 -> hi/lo)
    #pragma unroll
    for (int rep = 0; rep < 4; ++rep) {
      int idx = tid + rep * 256;
      int row = idx >> 3, q = idx & 7;
      float4 v = *(const float4*)(P.Af + (long)(m0 + row) * P.aLd + k0 + q * 4);
      int off = row * 32 + (((q >> 1) ^ ((row >> 1) & 3)) << 3) + ((q & 1) << 2);
      ushort_t hh[4], ll[4];
      split4(v, hh, ll);
      *(uint2*)(Ah + off) = *(uint2*)hh;
      *(uint2*)(Al + off) = *(uint2*)ll;
    }
    // stage B
    if constexpr (BM == 0) {
      #pragma unroll
      for (int rep = 0; rep < 4; ++rep) {
        int idx = tid + rep * 256;
        int row = idx >> 3, q = idx & 7;
        float4 v = *(const float4*)(P.Bf + (long)(n0 + row) * P.bLd + k0 + q * 4);
        int off = row * 32 + (((q >> 1) ^ ((row >> 1) & 3)) << 3) + ((q & 1) << 2);
        ushort_t hh[4], ll[4];
        split4(v, hh, ll);
        *(uint2*)(Bh + off) = *(uint2*)hh;
        *(uint2*)(Bl + off) = *(uint2*)ll;
      }
    } else {
      #pragma unroll
      for (int rep = 0; rep < 2; ++rep) {
        int idx = tid + rep * 256;
        int row = idx >> 2, h8 = idx & 3;
        int off = row * 32 + ((h8 ^ ((row >> 1) & 3)) << 3);
        long gsrc = (long)(n0 + row) * P.bLd + k0 + h8 * 8;
        *(uint4*)(Bh + off) = *(const uint4*)(P.Bhi + gsrc);
        *(uint4*)(Bl + off) = *(const uint4*)(P.Blo + gsrc);
      }
    }
    __syncthreads();

    bf16x8 ar[4], br[4];
    #pragma unroll
    for (int i = 0; i < 4; ++i) {
      int row = wm + i * 16 + lr;
      ar[i] = *(const bf16x8*)(Ah + row * 32 + ((g ^ ((row >> 1) & 3)) << 3));
    }
    #pragma unroll
    for (int j = 0; j < 4; ++j) {
      int row = wn + j * 16 + lr;
      br[j] = *(const bf16x8*)(Bh + row * 32 + ((g ^ ((row >> 1) & 3)) << 3));
    }
    #pragma unroll
    for (int i = 0; i < 4; ++i)
      #pragma unroll
      for (int j = 0; j < 4; ++j)
        acc[i][j] = __builtin_amdgcn_mfma_f32_16x16x32_bf16(ar[i], br[j], acc[i][j], 0, 0, 0);
    #pragma unroll
    for (int j = 0; j < 4; ++j) {
      int row = wn + j * 16 + lr;
      bf16x8 blv = *(const bf16x8*)(Bl + row * 32 + ((g ^ ((row >> 1) & 3)) << 3));
      #pragma unroll
      for (int i = 0; i < 4; ++i)
        acc[i][j] = __builtin_amdgcn_mfma_f32_16x16x32_bf16(ar[i], blv, acc[i][j], 0, 0, 0);
    }
    #pragma unroll
    for (int i = 0; i < 4; ++i) {
      int row = wm + i * 16 + lr;
      bf16x8 alv = *(const bf16x8*)(Al + row * 32 + ((g ^ ((row >> 1) & 3)) << 3));
      #pragma unroll
      for (int j = 0; j < 4; ++j)
        acc[i][j] = __builtin_amdgcn_mfma_f32_16x16x32_bf16(alv, br[j], acc[i][j], 0, 0, 0);
    }
    __syncthreads();
  }

  // epilogue: hi/lo store. C/D layout: col = lane&15, row = (lane>>4)*4 + reg.
  #pragma unroll
  for (int i = 0; i < 4; ++i) {
    #pragma unroll
    for (int j = 0; j < 4; ++j) {
      int colG = n0 + wn + j * 16 + lr;
      #pragma unroll
      for (int r = 0; r < 4; ++r) {
        int rowG = m0 + wm + i * 16 + g * 4 + r;
        float v = acc[i][j][r];
        ushort_t hi = f2bf(v);
        ushort_t lo = f2bf(v - bf2f(hi));
        long off;
        if (P.zMode) off = (long)(rowG >> 9) * 786432 + (long)(rowG & 511) * 1536 + colG;
        else         off = (long)rowG * P.cLd + colG;
        P.Chi[off] = hi;        // zMode: Clo = Chi + 768 -> lo half of slot row
        P.Clo[off] = lo;
      }
    }
  }
}

// ---------------------------------------------------------------------------
// fsc3: fused scores+softmax, bf16x3 exact. Block = 64 rows x 512 cols of one
// s (8 blocks/s, XCD-affine 1D grid: id%8 = s%8, tiles adjacent). 512 thr =
// 8 waves; wave w owns cols [w*64, w*64+64). A = Z from interleaved slots;
// B = X_s fp32 (d_in), split in staging. P bf16 written into the block's OWN
// row slots (bytes [0,1024) of each 3072B row) after all A-reads: race-free.
// ---------------------------------------------------------------------------
__global__ __launch_bounds__(512) void fsc3(ushort_t* __restrict__ slots,
                                            const float* __restrict__ X)
{
  __shared__ ushort_t lds[36864];   // Ah(2048)|Al(2048)|Bh(16384)|Bl(16384) = 72KB
  __shared__ float redf[64][12];
  __shared__ float reds[64][12];
  ushort_t* Ah = lds;
  ushort_t* Al = lds + 2048;
  ushort_t* Bh = lds + 4096;
  ushort_t* Bl = lds + 20480;

  const int id = blockIdx.x;
  const int c = id & 7, r = id >> 3;
  const int tile = r & 7;
  const int s = c + ((r >> 3) << 3);
  const int m0 = tile * 64;

  ushort_t* Az = slots + (long)s * 786432;       // slot rows: r*1536, hi|lo
  const float* Xf = X + (long)s * 393216;

  const int tid = threadIdx.x;
  const int lane = tid & 63;
  const int wave = tid >> 6;
  const int wn = wave * 64;
  const int lr = lane & 15, g = lane >> 4;

  f32x4 acc[4][4];
  #pragma unroll
  for (int i = 0; i < 4; ++i)
    #pragma unroll
    for (int j = 0; j < 4; ++j) {
      f32x4 zv = {0.f, 0.f, 0.f, 0.f};
      acc[i][j] = zv;
    }

  for (int k0 = 0; k0 < 768; k0 += 32) {
    // stage A: 64 rows, hi+lo (512 uint4 tasks, 1/thread)
    {
      int e = tid & 255;
      int row = e >> 2, h8 = e & 3;
      int off = row * 32 + ((h8 ^ ((row >> 1) & 3)) << 3);
      long src = (long)(m0 + row) * 1536 + k0 + h8 * 8;
      if (tid < 256) *(uint4*)(Ah + off) = *(const uint4*)(Az + src);
      else           *(uint4*)(Al + off) = *(const uint4*)(Az + src + 768);
    }
    // stage B: 512 rows fp32 -> split (4096 float4 tasks, 8/thread)
    #pragma unroll
    for (int rep = 0; rep < 8; ++rep) {
      int idx = tid + rep * 512;
      int row = idx >> 3, q = idx & 7;
      float4 v = *(const float4*)(Xf + (long)row * 768 + k0 + q * 4);
      int off = row * 32 + (((q >> 1) ^ ((row >> 1) & 3)) << 3) + ((q & 1) << 2);
      ushort_t hh[4], ll[4];
      split4(v, hh, ll);
      *(uint2*)(Bh + off) = *(uint2*)hh;
      *(uint2*)(Bl + off) = *(uint2*)ll;
    }
    __syncthreads();

    bf16x8 arh[4], arl[4];
    #pragma unroll
    for (int i = 0; i < 4; ++i) {
      int row = i * 16 + lr;
      int off = row * 32 + ((g ^ ((row >> 1) & 3)) << 3);
      arh[i] = *(const bf16x8*)(Ah + off);
      arl[i] = *(const bf16x8*)(Al + off);
    }
    #pragma unroll
    for (int j = 0; j < 4; ++j) {
      int row = wn + j * 16 + lr;
      int off = row * 32 + ((g ^ ((row >> 1) & 3)) << 3);
      bf16x8 bh = *(const bf16x8*)(Bh + off);
      bf16x8 bl = *(const bf16x8*)(Bl + off);
      #pragma unroll
      for (int i = 0; i < 4; ++i) {
        acc[i][j] = __builtin_amdgcn_mfma_f32_16x16x32_bf16(arh[i], bh, acc[i][j], 0, 0, 0);
        acc[i][j] = __builtin_amdgcn_mfma_f32_16x16x32_bf16(arh[i], bl, acc[i][j], 0, 0, 0);
        acc[i][j] = __builtin_amdgcn_mfma_f32_16x16x32_bf16(arl[i], bh, acc[i][j], 0, 0, 0);
      }
    }
    __syncthreads();
  }

  // softmax over full rows (cross-wave via LDS)
  float mr[4][4];
  #pragma unroll
  for (int i = 0; i < 4; ++i)
    #pragma unroll
    for (int rg = 0; rg < 4; ++rg) {
      float mx = -3.0e38f;
      #pragma unroll
      for (int j = 0; j < 4; ++j) {
        acc[i][j][rg] *= SCALE;
        mx = fmaxf(mx, acc[i][j][rg]);
      }
      #pragma unroll
      for (int off = 8; off >= 1; off >>= 1) mx = fmaxf(mx, __shfl_xor(mx, off, 64));
      if (lr == 0) redf[i * 16 + g * 4 + rg][wave] = mx;
    }
  __syncthreads();
  #pragma unroll
  for (int i = 0; i < 4; ++i)
    #pragma unroll
    for (int rg = 0; rg < 4; ++rg) {
      int row = i * 16 + g * 4 + rg;
      float4 a = *(const float4*)&redf[row][0];
      float4 b = *(const float4*)&redf[row][4];
      mr[i][rg] = fmaxf(fmaxf(fmaxf(a.x, a.y), fmaxf(a.z, a.w)),
                        fmaxf(fmaxf(b.x, b.y), fmaxf(b.z, b.w)));
    }
  #pragma unroll
  for (int i = 0; i < 4; ++i)
    #pragma unroll
    for (int rg = 0; rg < 4; ++rg) {
      float sm = 0.f;
      #pragma unroll
      for (int j = 0; j < 4; ++j) {
        float e = __expf(acc[i][j][rg] - mr[i][rg]);
        acc[i][j][rg] = e;
        sm += e;
      }
      #pragma unroll
      for (int off = 8; off >= 1; off >>= 1) sm += __shfl_xor(sm, off, 64);
      if (lr == 0) reds[i * 16 + g * 4 + rg][wave] = sm;
    }
  __syncthreads();
  #pragma unroll
  for (int i = 0; i < 4; ++i)
    #pragma unroll
    for (int rg = 0; rg < 4; ++rg) {
      int row = i * 16 + g * 4 + rg;
      float4 a = *(const float4*)&reds[row][0];
      float4 b = *(const float4*)&reds[row][4];
      float inv = 1.0f / (a.x + a.y + a.z + a.w + b.x + b.y + b.z + b.w);
      #pragma unroll
      for (int j = 0; j < 4; ++j)
        Az[(long)(m0 + row) * 1536 + wn + j * 16 + lr] = f2bf(acc[i][j][rg] * inv);
    }
}

// ---------------------------------------------------------------------------
// pv: out_s = P * X_s. Block = 64 rows x ALL 768 cols of one s (8 blocks/s,
// XCD-affine). 768 thr = 12 waves; wave w owns cols [w*64, w*64+64).
// P (A, K=512) staged ONCE to swizzled LDS before any write. B-frags built
// from strided fp32 X loads + cvt_pk (col-coalesced across lanes). Out fp32
// overwrites the block's own row slots entirely -> safe after LDS staging.
// ---------------------------------------------------------------------------
__global__ __launch_bounds__(768) void pv(float* __restrict__ outp,
                                          const float* __restrict__ X)
{
  __shared__ ushort_t Pa[32768];   // 64 rows x 512, swizzled (64 KB)

  const int id = blockIdx.x;
  const int c = id & 7, r = id >> 3;
  const int tile = r & 7;
  const int s = c + ((r >> 3) << 3);
  const int m0 = tile * 64;

  const ushort_t* Ps = (const ushort_t*)outp + (long)s * 786432;
  const float* Xf = X + (long)s * 393216;

  const int tid = threadIdx.x;
  const int lane = tid & 63;
  const int wave = tid >> 6;
  const int wn = wave * 64;
  const int lr = lane & 15, g = lane >> 4;

  // stage P rows m0..m0+63 (4096 uint4 tasks)
  for (int idx = tid; idx < 4096; idx += 768) {
    int row = idx >> 6, h8 = idx & 63;
    int off = row * 512 + ((h8 ^ (row & 7)) << 3);
    *(uint4*)(Pa + off) = *(const uint4*)(Ps + (long)(m0 + row) * 1536 + h8 * 8);
  }
  __syncthreads();

  f32x4 acc[4][4];
  #pragma unroll
  for (int i = 0; i < 4; ++i)
    #pragma unroll
    for (int j = 0; j < 4; ++j) {
      f32x4 zv = {0.f, 0.f, 0.f, 0.f};
      acc[i][j] = zv;
    }

  for (int kk = 0; kk < 16; ++kk) {
    const int k0 = kk * 32;
    bf16x8 ar[4];
    #pragma unroll
    for (int i = 0; i < 4; ++i) {
      int row = i * 16 + lr;
      ar[i] = *(const bf16x8*)(Pa + row * 512 + (((kk * 4 + g) ^ (row & 7)) << 3));
    }
    #pragma unroll
    for (int j = 0; j < 4; ++j) {
      int col = wn + j * 16 + lr;
      float xv[8];
      #pragma unroll
      for (int i = 0; i < 8; ++i)
        xv[i] = Xf[(long)(k0 + g * 8 + i) * 768 + col];
      unsigned w[4];
      #pragma unroll
      for (int p = 0; p < 4; ++p) {
        __hip_bfloat162 hb = __float22bfloat162_rn(make_float2(xv[2 * p], xv[2 * p + 1]));
        w[p] = *(unsigned*)&hb;
      }
      bf16x8 bv = *(bf16x8*)w;
      #pragma unroll
      for (int i = 0; i < 4; ++i)
        acc[i][j] = __builtin_amdgcn_mfma_f32_16x16x32_bf16(ar[i], bv, acc[i][j], 0, 0, 0);
    }
  }

  float* Co = outp + (long)s * 393216;
  #pragma unroll
  for (int i = 0; i < 4; ++i)
    #pragma unroll
    for (int j = 0; j < 4; ++j) {
      int colG = wn + j * 16 + lr;
      #pragma unroll
      for (int rg = 0; rg < 4; ++rg) {
        int rowG = m0 + i * 16 + g * 4 + rg;
        Co[(long)rowG * 768 + colG] = acc[i][j][rg];
      }
    }
}

// ---------------------------------------------------------------------------
extern "C" void kernel_launch(void* const* d_in, const int* in_sizes, int n_in,
                              void* d_out, int out_size, void* d_ws, size_t ws_size,
                              hipStream_t stream) {
  const float* X = (const float*)d_in[0];
  const float* R = (const float*)d_in[1];  // rotation_params
  const float* W = (const float*)d_in[2];  // entangle_params

  // ws: only H hi/lo planes (768x768 each, 2.25 MB)
  ushort_t* Hhi = (ushort_t*)d_ws;
  ushort_t* Hlo = Hhi + 768 * 768;

  // K0: H = W * R^T (planar hi/lo in ws)
  {
    MMP p{};
    p.Af = W; p.aLd = 768;
    p.Bf = R; p.bLd = 768;
    p.Chi = Hhi; p.Clo = Hlo; p.cLd = 768; p.zMode = 0;
    p.K = 768;
    mm<0><<<dim3(6, 6), 256, 0, stream>>>(p);
  }
  // K1: Z = X * H^T -> row-interleaved slots filling all of d_out
  {
    MMP p{};
    p.Af = X; p.aLd = 768;
    p.Bhi = Hhi; p.Blo = Hlo; p.bLd = 768;
    p.Chi = (ushort_t*)d_out;
    p.Clo = (ushort_t*)d_out + 768;   // lo half of each 1536-ushort row slot
    p.zMode = 1;
    p.K = 768;
    mm<1><<<dim3(6, 2048), 256, 0, stream>>>(p);
  }
  // K2: fused scores+softmax -> P into slots (all s)
  fsc3<<<dim3(4096), 512, 0, stream>>>((ushort_t*)d_out, X);
  // K3: out = P * V, overwriting slots with final fp32 (all s)
  pv<<<dim3(4096), 768, 0, stream>>>((float*)d_out, X);
}